// Round 10
// baseline (486.591 us; speedup 1.0000x reference)
//
#include <hip/hip_runtime.h>
#include <math.h>

// ---------------------------------------------------------------------------
// SNN generator. Round 17: rest-side structural cuts (conv1 frozen at R14,
// measured 133us = 36% dense peak = the 2-phase plain-HIP ceiling).
//  - k_pre: horizontal fusion of lin_bn1 (blocks 0..127) and wtrans
//    (blocks 128..6527) -- independent DAG branches, now overlapped; node -1.
//  - bn3 + y2n ELIMINATED: conv2 accumulates per-channel sum/sumsq of its
//    own output (wave shfl-reduce + 8 atomicAdds/wave into stats[128],
//    zeroed by bn2_up); conv3 builds coef/beta in LDS from stats and applies
//    BN3+leaky inline on predicated y2 reads (OOB tap = 0 = conv zero-pad,
//    matching reference semantics). Node -1, y2n round-trip gone.
//  - 6 nodes total (was 8).
//
// Workspace (95.9 MB):
//   wT    f16 [9][128][25632]   at 0           59,056,128 B
//   spkTb u8  [324][25664]      at 59,056,128   8,315,136 B
//   I     f32                   at 67,633,408   1,048,576 B
//   y1p   f16 [48][8][128][256] at 69,730,560  25,165,824 B
//  phase B (aliases wT after conv1):
//   x2p   f32                   at 0            4,734,976 B
//   y2    f32                   at 4,734,976    2,097,152 B
//   stats f32 [128]             at 6,832,128          512 B
// ---------------------------------------------------------------------------

#define WROW 25632      // f16 elems per wT row (801 cache lines)
#define SROW 25664      // bytes per spkTb row (401 cache lines)

typedef _Float16 half8 __attribute__((ext_vector_type(8)));
typedef float f32x4 __attribute__((ext_vector_type(4)));
typedef unsigned int uint4v __attribute__((ext_vector_type(4)));

union AFrag { uint4v u4; unsigned int u[4]; half8 h; };

// Horizontal fusion: blocks 0..127 = lin_bn1 (ch = blockIdx.x);
// blocks 128..6527 = wtrans (wid = blockIdx.x - 128).
__global__ __launch_bounds__(256) void k_pre(
    const float* __restrict__ wc1, _Float16* __restrict__ wT,
    const float* __restrict__ z, const float* __restrict__ wl1,
    const float* __restrict__ bl1, const float* __restrict__ g1,
    const float* __restrict__ be1, float* __restrict__ I) {
  __shared__ float smem[4608];   // 18,432 B: wtrans t[2][2304] / lin red[256]
  int tid = threadIdx.x;
  if (blockIdx.x < 128) {
    // ---- fused linear (z @ w_l1 + b_l1) + BN1 + upsample2x -> I ----
    int ch = blockIdx.x;
    float* red = smem;
    int hw = tid & 63, b0 = tid >> 6;
    int j = ch * 64 + hw;
    float acc0 = bl1[j], acc1 = acc0;
    const float* zp0 = z + b0 * 100;
    const float* zp1 = z + (b0 + 4) * 100;
    for (int l = 0; l < 100; ++l) {
      float wv = wl1[l * 8192 + j];
      acc0 += zp0[l] * wv;
      acc1 += zp1[l] * wv;
    }
    float v0 = acc0, v1 = acc1;
    red[tid] = v0 + v1; __syncthreads();
    for (int s = 128; s > 0; s >>= 1) { if (tid < s) red[tid] += red[tid + s]; __syncthreads(); }
    float mean = red[0] * (1.0f / 512.0f);
    __syncthreads();
    float d0 = v0 - mean, d1 = v1 - mean;
    red[tid] = d0 * d0 + d1 * d1; __syncthreads();
    for (int s = 128; s > 0; s >>= 1) { if (tid < s) red[tid] += red[tid + s]; __syncthreads(); }
    float var = red[0] * (1.0f / 512.0f);
    float coef = g1[ch] / sqrtf(var + 1e-5f);
    float beta = be1[ch];
    float q0 = (v0 - mean) * coef + beta;
    float q1 = (v1 - mean) * coef + beta;
#pragma unroll
    for (int k = 0; k < 2; ++k) {
      int n = k ? (tid + 256) : tid; float q = k ? q1 : q0;
      int b = n >> 6, hh = n & 63, h = hh >> 3, ww = hh & 7;
      float* o = I + (size_t)(b * 128 + ch) * 256 + (2 * h) * 16 + 2 * ww;
      o[0] = q; o[1] = q; o[16] = q; o[17] = q;
    }
  } else {
    // ---- weight transform: w_c1 fp32 -> wT[tap][oc][c] f16, u32 writes ----
    int wid = blockIdx.x - 128;
    float (*t)[2304] = (float(*)[2304])smem;
    int op = wid / 100, cg = wid % 100;
    int oc0 = op * 2, c0 = cg * 256;
    const float* src = wc1 + (size_t)oc0 * 230400 + (size_t)c0 * 9;
#pragma unroll
    for (int i = 0; i < 9; ++i) {
      t[0][tid + i * 256] = src[tid + i * 256];
      t[1][tid + i * 256] = src[230400 + tid + i * 256];
    }
    __syncthreads();
    int oh = tid >> 7;           // oc sub-index (0/1)
    int cp = tid & 127;          // c pair: c = 2cp, 2cp+1
#pragma unroll
    for (int tap = 0; tap < 9; ++tap) {
      union { unsigned int u; _Float16 h[2]; } pk;
      pk.h[0] = (_Float16)t[oh][(2 * cp) * 9 + tap];
      pk.h[1] = (_Float16)t[oh][(2 * cp + 1) * 9 + tap];
      *(unsigned int*)((char*)wT +
          ((size_t)(tap * 128 + oc0 + oh) * WROW + c0 + 2 * cp) * 2) = pk.u;
    }
  }
}

// LIF with bit-packed transposed spike output + fused halo zeroing.
// spkTb[pos][col/8] bit (col&7), col = t*1024 + plane.
__global__ __launch_bounds__(256) void k_lif(
    const float* __restrict__ I, unsigned char* __restrict__ spkTb) {
  int g = blockIdx.x * 256 + threadIdx.x;
  if (g < 217600) {
    int hr = g / 3200;           // halo row index 0..67
    int i  = g - hr * 3200;      // u64 index within row
    int row;
    if (hr < 18)      row = hr;                    // top band a=0
    else if (hr < 36) row = 306 + (hr - 18);       // bottom band a=17
    else { int kk = hr - 36; row = ((kk >> 1) + 1) * 18 + ((kk & 1) ? 17 : 0); }
    *(unsigned long long*)(spkTb + (size_t)row * SROW + (size_t)i * 8) = 0ULL;
  }
  int px = g >> 10, plane = g & 1023;
  int lane = threadIdx.x & 63;
  float in = I[plane * 256 + px];
  int pos = ((px >> 4) + 1) * 18 + (px & 15) + 1;
  unsigned long long* wsrow =
      (unsigned long long*)(spkTb + (size_t)pos * SROW + ((plane - lane) >> 3));
  float mem = 0.0f;
  for (int t = 0; t < 200; ++t) {
    float reset = (mem > 1.0f) ? 1.0f : 0.0f;
    mem = 0.95f * mem + in - reset;
    unsigned long long m = __ballot(mem > 1.0f);
    if (lane == 0) wsrow[t * 16] = m;   // t*128 bytes
  }
}

// bit->f16 expand: byte b -> 8 halfs {0,1.0h}, via multiply-spread + v_perm.
__device__ inline void expandp(unsigned int b, AFrag& f) {
  unsigned int lo = ((b & 0xFu) * 0x00204081u) & 0x01010101u;
  unsigned int hi = ((b >> 4) * 0x00204081u) & 0x01010101u;
  lo *= 0x3Cu; hi *= 0x3Cu;
  f.u[0] = __builtin_amdgcn_perm(0u, lo, 0x01040004u);
  f.u[1] = __builtin_amdgcn_perm(0u, lo, 0x03040204u);
  f.u[2] = __builtin_amdgcn_perm(0u, hi, 0x01040004u);
  f.u[3] = __builtin_amdgcn_perm(0u, hi, 0x03040204u);
}

__device__ __forceinline__ void gll16(const void* g, void* l) {
  __builtin_amdgcn_global_load_lds(
      (const __attribute__((address_space(1))) unsigned int*)g,
      (__attribute__((address_space(3))) unsigned int*)l, 16, 0, 0);
}

// conv1 implicit GEMM (R14 structure, FROZEN -- measured 133us, 36% dense
// peak = 2-phase plain-HIP ceiling). grid 768 = 48 K-slices x (2 ocHalf x
// 8 b), XCD-grouped by slice; 256 thr / 4 waves. Block tile M64 x N256;
// wave = M64 x N64 (mt=4, nt=4). K-slice: whole 128-ch chunks
// q in [sl*25/6,(sl+1)*25/6) (4 or 5); NBS = 9 taps x qc. 2-phase loop,
// A dbuf in LDS (2x16KB), B per-bigstep. LDS A chunk [oc 64][ch 128] f16,
// 4-bit 16B-slot XOR swizzle (slot ^= oc&15) on source AND ds_read address.
__global__ __launch_bounds__(256, 3) void k_conv1_mfma(
    const unsigned char* __restrict__ spkTb, const _Float16* __restrict__ wT,
    _Float16* __restrict__ y1p) {
  // bijective XCD swizzle: 768 = 8 x 96; XCD x gets v in [96x, 96x+96)
  int v = (blockIdx.x & 7) * 96 + (blockIdx.x >> 3);
  int sl = v >> 4;                       // 0..47
  int r = v & 15;
  int half = r >> 3, b = r & 7;          // oc-half, single batch
  int tid = threadIdx.x;
  int wave = tid >> 6, lane = tid & 63;
  int quad = lane >> 4, l16 = lane & 15;
  int qs = quad * 8;
  int h0 = wave * 4;

  int q0 = (sl * 25) / 6;
  int qc = ((sl + 1) * 25) / 6 - q0;     // 4 or 5 chunks of 128 ch
  int NBS = 9 * qc;

  __shared__ _Float16 As[2][8192];   // 2 x 16 KB, [oc 64][ch 128] swizzled

  int ocl = tid >> 4;
  int sc0 = (tid & 15) ^ ocl;
  const char* srcA0 = (const char*)wT + (size_t)q0 * 256
                    + (size_t)(half * 64 + ocl) * (WROW * 2) + sc0 * 16;

  const unsigned char* rowp[4];
#pragma unroll
  for (int nt = 0; nt < 4; ++nt)
    rowp[nt] = spkTb + b * 3200 + q0 * 16
             + (size_t)((h0 + nt) * 18 + l16) * SROW;

  int dsb[4];
#pragma unroll
  for (int s = 0; s < 4; ++s)
    dsb[s] = l16 * 256 + ((s * 64 + quad * 16) ^ (l16 << 4));

  f32x4 acc[4][4] = {};                 // [mt][nt]

  // prologue: stage A(step 0: tap 0, qi 0) -> buffer 0
#pragma unroll
  for (int i = 0; i < 4; ++i)
    gll16(srcA0 + (size_t)i * (16 * WROW * 2), (char*)As + i * 4096 + wave * 1024);
  __syncthreads();

  int tap = 0, qi = 0;
  for (int k = 0; k < NBS; ++k) {
    int dh = tap / 3, dw = tap - dh * 3;
    uint4v bx[4];
    int boff = (dh * 18 + dw) * SROW + qi * 16;
#pragma unroll
    for (int nt = 0; nt < 4; ++nt)
      bx[nt] = *(const uint4v*)(rowp[nt] + boff);
    int qin = qi + 1, tapn = tap;
    if (qin == qc) { qin = 0; tapn = tap + 1; }
    if (k + 1 < NBS) {
      size_t aoff = (size_t)tapn * ((size_t)128 * WROW * 2) + (size_t)qin * 256;
      char* dst = (char*)As + ((k + 1) & 1) * 16384 + wave * 1024;
#pragma unroll
      for (int i = 0; i < 4; ++i)
        gll16(srcA0 + (size_t)i * (16 * WROW * 2) + aoff, dst + i * 4096);
    }
    const char* cA = (const char*)As + (k & 1) * 16384;
#pragma unroll
    for (int s = 0; s < 4; ++s) {
      AFrag a[4];
#pragma unroll
      for (int mt = 0; mt < 4; ++mt)
        a[mt].u4 = *(const uint4v*)(cA + dsb[s] + mt * 4096);
#pragma unroll
      for (int nt = 0; nt < 4; ++nt) {
        AFrag bf; expandp((bx[nt][s] >> qs) & 0xFFu, bf);
#pragma unroll
        for (int mt = 0; mt < 4; ++mt)
          acc[mt][nt] = __builtin_amdgcn_mfma_f32_16x16x32_f16(
              a[mt].h, bf.h, acc[mt][nt], 0, 0, 0);
      }
    }
    __syncthreads();
    tap = tapn; qi = qin;
  }

  // epilogue: f16 partials
  _Float16* ob = y1p + (size_t)(sl * 8 + b) * 32768 + half * 16384;
#pragma unroll
  for (int mt = 0; mt < 4; ++mt)
#pragma unroll
    for (int nt = 0; nt < 4; ++nt) {
      int px = (h0 + nt) * 16 + l16;
#pragma unroll
      for (int rr = 0; rr < 4; ++rr) {
        int oc = mt * 16 + quad * 4 + rr;
        ob[(size_t)oc * 256 + px] = (_Float16)acc[mt][nt][rr];
      }
    }
}

// BN2 (eps 0.8, stats over 2048) + 48-way y1p reduce + conv1 bias +
// leaky(0.2) + upsample2x + halo zero + stats-buffer zero.
__global__ __launch_bounds__(256) void k_bn2_up(
    const _Float16* __restrict__ y1p, const float* __restrict__ bc1,
    const float* __restrict__ g2, const float* __restrict__ be2,
    float* __restrict__ x2p, float* __restrict__ stats) {
  int ch = blockIdx.x, tid = threadIdx.x;
  __shared__ float red[256];

  if (blockIdx.x == 0 && tid < 128) stats[tid] = 0.0f;  // for conv2 atomics

  // halo zero: planes (b, ch), 132-elem ring each
  for (int e = tid; e < 1056; e += 256) {
    int b = e / 132, i = e - b * 132;
    int rr, cc;
    if (i < 34)       { rr = 0;       cc = i; }
    else if (i < 68)  { rr = 33;      cc = i - 34; }
    else if (i < 100) { rr = i - 67;  cc = 0; }
    else              { rr = i - 99;  cc = 33; }
    x2p[(size_t)(b * 128 + ch) * 1156 + rr * 34 + cc] = 0.0f;
  }

  int pp = tid & 127;          // px pair: px = 2pp, 2pp+1
  int bh = tid >> 7;           // batches bh*4 .. bh*4+3
  float bias = bc1[ch];
  float a[4][2] = {};
  const char* base = (const char*)y1p + ((size_t)ch * 256 + pp * 2) * 2
                   + (size_t)bh * 4 * 65536;
  for (int tl = 0; tl < 48; ++tl) {
    const char* q = base + (size_t)tl * 524288;
#pragma unroll
    for (int k = 0; k < 4; ++k) {
      union { unsigned int u; _Float16 h[2]; } cv;
      cv.u = *(const unsigned int*)(q + (size_t)k * 65536);
      a[k][0] += (float)cv.h[0];
      a[k][1] += (float)cv.h[1];
    }
  }
  float vv[4][2]; float s = 0.0f;
#pragma unroll
  for (int k = 0; k < 4; ++k)
#pragma unroll
    for (int e = 0; e < 2; ++e) { vv[k][e] = a[k][e] + bias; s += vv[k][e]; }

  red[tid] = s; __syncthreads();
  for (int st = 128; st > 0; st >>= 1) { if (tid < st) red[tid] += red[tid + st]; __syncthreads(); }
  float mean = red[0] * (1.0f / 2048.0f);
  __syncthreads();
  s = 0.0f;
#pragma unroll
  for (int k = 0; k < 4; ++k)
#pragma unroll
    for (int e = 0; e < 2; ++e) { float d = vv[k][e] - mean; s += d * d; }
  red[tid] = s; __syncthreads();
  for (int st = 128; st > 0; st >>= 1) { if (tid < st) red[tid] += red[tid + st]; __syncthreads(); }
  float var = red[0] * (1.0f / 2048.0f);
  float coef = g2[ch] / sqrtf(var + 0.8f);
  float beta = be2[ch];
#pragma unroll
  for (int k = 0; k < 4; ++k)
#pragma unroll
    for (int e = 0; e < 2; ++e) {
      int b = bh * 4 + k, px = pp * 2 + e, h = px >> 4, w = px & 15;
      float q = (vv[k][e] - mean) * coef + beta;
      q = (q >= 0.0f) ? q : 0.2f * q;
      float* o = x2p + (size_t)(b * 128 + ch) * 1156 + (2 * h + 1) * 34 + (2 * w + 1);
      o[0] = q; o[1] = q; o[34] = q; o[35] = q;
    }
}

// conv2: flat grid 512, b = id&7 (XCD-by-batch); octile = (id>>3)>>2,
// pq = (id>>3)&3. Thread = 1 px x 4 oc. Also accumulates BN3 stats
// (sum, sumsq per oc) via wave shfl-reduce + atomics (replaces k_bn3).
__global__ __launch_bounds__(256) void k_conv2(
    const float* __restrict__ x2p, const float* __restrict__ wc2,
    const float* __restrict__ bc2, float* __restrict__ y2,
    float* __restrict__ stats) {
  int b = blockIdx.x & 7;
  int rem = blockIdx.x >> 3;
  int octile = rem >> 2, pq = rem & 3;
  int tid = threadIdx.x;
  int p = pq * 256 + tid, h = p >> 5, w = p & 31;
  float a0 = 0.0f, a1 = 0.0f, a2 = 0.0f, a3 = 0.0f;
  const float* base = x2p + (size_t)(b * 128) * 1156 + h * 34 + w;
  const float* wb = wc2 + (size_t)(octile * 4) * 128 * 9;
  for (int ch = 0; ch < 128; ++ch) {
    const float* pp = base + (size_t)ch * 1156;
    float s0 = pp[0],  s1 = pp[1],  s2 = pp[2];
    float s3 = pp[34], s4 = pp[35], s5 = pp[36];
    float s6 = pp[68], s7 = pp[69], s8 = pp[70];
    const float* w0 = wb + (size_t)ch * 9;
    const float* w1 = wb + (size_t)(128 + ch) * 9;
    const float* w2 = wb + (size_t)(256 + ch) * 9;
    const float* w3 = wb + (size_t)(384 + ch) * 9;
    a0 += s0*w0[0]+s1*w0[1]+s2*w0[2]+s3*w0[3]+s4*w0[4]+s5*w0[5]+s6*w0[6]+s7*w0[7]+s8*w0[8];
    a1 += s0*w1[0]+s1*w1[1]+s2*w1[2]+s3*w1[3]+s4*w1[4]+s5*w1[5]+s6*w1[6]+s7*w1[7]+s8*w1[8];
    a2 += s0*w2[0]+s1*w2[1]+s2*w2[2]+s3*w2[3]+s4*w2[4]+s5*w2[5]+s6*w2[6]+s7*w2[7]+s8*w2[8];
    a3 += s0*w3[0]+s1*w3[1]+s2*w3[2]+s3*w3[3]+s4*w3[4]+s5*w3[5]+s6*w3[6]+s7*w3[7]+s8*w3[8];
  }
  int oc0 = octile * 4;
  float v0 = a0 + bc2[oc0 + 0];
  float v1 = a1 + bc2[oc0 + 1];
  float v2 = a2 + bc2[oc0 + 2];
  float v3 = a3 + bc2[oc0 + 3];
  y2[(size_t)(b * 64 + oc0 + 0) * 1024 + p] = v0;
  y2[(size_t)(b * 64 + oc0 + 1) * 1024 + p] = v1;
  y2[(size_t)(b * 64 + oc0 + 2) * 1024 + p] = v2;
  y2[(size_t)(b * 64 + oc0 + 3) * 1024 + p] = v3;
  // BN3 stats: per-wave reduce of 8 quantities, one atomic set per wave
  float q0 = v0 * v0, q1 = v1 * v1, q2 = v2 * v2, q3 = v3 * v3;
#pragma unroll
  for (int off = 32; off > 0; off >>= 1) {
    v0 += __shfl_down(v0, off); q0 += __shfl_down(q0, off);
    v1 += __shfl_down(v1, off); q1 += __shfl_down(q1, off);
    v2 += __shfl_down(v2, off); q2 += __shfl_down(q2, off);
    v3 += __shfl_down(v3, off); q3 += __shfl_down(q3, off);
  }
  if ((tid & 63) == 0) {
    atomicAdd(&stats[oc0 + 0], v0); atomicAdd(&stats[64 + oc0 + 0], q0);
    atomicAdd(&stats[oc0 + 1], v1); atomicAdd(&stats[64 + oc0 + 1], q1);
    atomicAdd(&stats[oc0 + 2], v2); atomicAdd(&stats[64 + oc0 + 2], q2);
    atomicAdd(&stats[oc0 + 3], v3); atomicAdd(&stats[64 + oc0 + 3], q3);
  }
}

// conv3 (3 oc) + bias + tanh -> d_out (8,3,32,32), with BN3 (eps 0.8)
// + leaky applied INLINE from stats (replaces k_bn3 + y2n). OOB taps = 0
// (conv zero-padding semantics). flat grid 128: b = id&7, pg = id>>3.
// 256 thr = 64 px x 4 ch-groups; LDS reduce.
__global__ __launch_bounds__(256) void k_conv3(
    const float* __restrict__ y2, const float* __restrict__ stats,
    const float* __restrict__ g3, const float* __restrict__ be3,
    const float* __restrict__ wc3, const float* __restrict__ bc3,
    float* __restrict__ out) {
  __shared__ float cA[64], cB[64];
  int tid = threadIdx.x;
  if (tid < 64) {
    float mean = stats[tid] * (1.0f / 8192.0f);
    float var = stats[64 + tid] * (1.0f / 8192.0f) - mean * mean;
    float coef = g3[tid] / sqrtf(var + 0.8f);
    cA[tid] = coef;
    cB[tid] = be3[tid] - mean * coef;
  }
  __syncthreads();
  int b = blockIdx.x & 7, pg = blockIdx.x >> 3;
  int pxl = tid & 63, cg = tid >> 6;
  int p = pg * 64 + pxl, h = p >> 5, w = p & 31;
  float a0 = 0.0f, a1 = 0.0f, a2 = 0.0f;
  const float* ybase = y2 + (size_t)(b * 64 + cg * 16) * 1024;
  for (int c = 0; c < 16; ++c) {
    int ch = cg * 16 + c;
    const float* pl = ybase + (size_t)c * 1024;
    float ca = cA[ch], cb = cB[ch];
    float s[9];
#pragma unroll
    for (int dh = 0; dh < 3; ++dh)
#pragma unroll
      for (int dwi = 0; dwi < 3; ++dwi) {
        int hh = h + dh - 1, ww = w + dwi - 1;
        float v = 0.0f;
        if (hh >= 0 && hh < 32 && ww >= 0 && ww < 32) {
          float t = pl[hh * 32 + ww] * ca + cb;
          v = (t >= 0.0f) ? t : 0.2f * t;
        }
        s[dh * 3 + dwi] = v;
      }
    const float* w0 = wc3 + (size_t)ch * 9;
    const float* w1 = wc3 + (size_t)(64 + ch) * 9;
    const float* w2 = wc3 + (size_t)(128 + ch) * 9;
    a0 += s[0]*w0[0]+s[1]*w0[1]+s[2]*w0[2]+s[3]*w0[3]+s[4]*w0[4]+s[5]*w0[5]+s[6]*w0[6]+s[7]*w0[7]+s[8]*w0[8];
    a1 += s[0]*w1[0]+s[1]*w1[1]+s[2]*w1[2]+s[3]*w1[3]+s[4]*w1[4]+s[5]*w1[5]+s[6]*w1[6]+s[7]*w1[7]+s[8]*w1[8];
    a2 += s[0]*w2[0]+s[1]*w2[1]+s[2]*w2[2]+s[3]*w2[3]+s[4]*w2[4]+s[5]*w2[5]+s[6]*w2[6]+s[7]*w2[7]+s[8]*w2[8];
  }
  __shared__ float red[3][256];
  red[0][tid] = a0; red[1][tid] = a1; red[2][tid] = a2;
  __syncthreads();
  if (tid < 192) {
    int oc = tid >> 6, px = tid & 63;
    float sres = red[oc][px] + red[oc][px + 64] + red[oc][px + 128] + red[oc][px + 192];
    out[(size_t)(b * 3 + oc) * 1024 + pg * 64 + px] = tanhf(sres + bc3[oc]);
  }
}

extern "C" void kernel_launch(void* const* d_in, const int* in_sizes, int n_in,
                              void* d_out, int out_size, void* d_ws, size_t ws_size,
                              hipStream_t stream) {
  const float* z    = (const float*)d_in[0];
  const float* w_l1 = (const float*)d_in[1];
  const float* b_l1 = (const float*)d_in[2];
  const float* g1   = (const float*)d_in[3];
  const float* be1  = (const float*)d_in[4];
  const float* w_c1 = (const float*)d_in[5];
  const float* b_c1 = (const float*)d_in[6];
  const float* g2   = (const float*)d_in[7];
  const float* be2  = (const float*)d_in[8];
  const float* w_c2 = (const float*)d_in[9];
  const float* b_c2 = (const float*)d_in[10];
  const float* g3   = (const float*)d_in[11];
  const float* be3  = (const float*)d_in[12];
  const float* w_c3 = (const float*)d_in[13];
  const float* b_c3 = (const float*)d_in[14];
  float* out = (float*)d_out;

  char* ws = (char*)d_ws;
  // phase A
  _Float16* wT = (_Float16*)ws;                             // 59,056,128 B
  unsigned char* spkTb = (unsigned char*)(ws + 59056128);   //  8,315,136 B
  float* I   = (float*)(ws + 67633408);                     //  1,048,576 B
  _Float16* y1p = (_Float16*)(ws + 69730560);               // 25,165,824 B
  // phase B (aliases wT region; written only after conv1 completes)
  float* x2p   = (float*)ws;                                //  4,734,976 B
  float* y2    = (float*)(ws + 4734976);                    //  2,097,152 B
  float* stats = (float*)(ws + 6832128);                    //        512 B

  k_pre    <<<6528, 256, 0, stream>>>(w_c1, wT, z, w_l1, b_l1, g1, be1, I);
  k_lif    <<<1024, 256, 0, stream>>>(I, spkTb);
  k_conv1_mfma<<<768, 256, 0, stream>>>(spkTb, wT, y1p);

  k_bn2_up <<<128, 256, 0, stream>>>(y1p, b_c1, g2, be2, x2p, stats);
  k_conv2  <<<512, 256, 0, stream>>>(x2p, w_c2, b_c2, y2, stats);
  k_conv3  <<<128, 256, 0, stream>>>(y2, stats, g3, be3, w_c3, b_c3, out);
}

// Round 11
// 424.634 us; speedup vs baseline: 1.1459x; 1.1459x over previous
//
#include <hip/hip_runtime.h>
#include <math.h>

// ---------------------------------------------------------------------------
// SNN generator. Round 18: bisect R17's +53us regression. Base = R16
// (verified 430.8us) + ONLY the k_pre horizontal fusion (wtrans || lin_bn1,
// no new contention mechanism). R17's conv2 stats atomics (16K cross-XCD
// atomicAdds onto 8 cache lines) and conv3 predicated inline-BN are REVERTED
// -- prime suspects for the regression. bn3 restored as standalone kernel.
//
// Workspace (95.9 MB):
//   wT    f16 [9][128][25632]   at 0           59,056,128 B
//   spkTb u8  [324][25664]      at 59,056,128   8,315,136 B
//   I     f32                   at 67,633,408   1,048,576 B
//   y1p   f16 [48][8][128][256] at 69,730,560  25,165,824 B
//  phase B (aliases wT after conv1): x2p, y2n, y2 at 0..9,199,616 B
// ---------------------------------------------------------------------------

#define WROW 25632      // f16 elems per wT row (801 cache lines)
#define SROW 25664      // bytes per spkTb row (401 cache lines)

typedef _Float16 half8 __attribute__((ext_vector_type(8)));
typedef float f32x4 __attribute__((ext_vector_type(4)));
typedef unsigned int uint4v __attribute__((ext_vector_type(4)));

union AFrag { uint4v u4; unsigned int u[4]; half8 h; };

// Horizontal fusion: blocks 0..127 = lin_bn1 (ch = blockIdx.x);
// blocks 128..6527 = wtrans (wid = blockIdx.x - 128).
__global__ __launch_bounds__(256) void k_pre(
    const float* __restrict__ wc1, _Float16* __restrict__ wT,
    const float* __restrict__ z, const float* __restrict__ wl1,
    const float* __restrict__ bl1, const float* __restrict__ g1,
    const float* __restrict__ be1, float* __restrict__ I) {
  __shared__ float smem[4608];   // 18,432 B: wtrans t[2][2304] / lin red[256]
  int tid = threadIdx.x;
  if (blockIdx.x < 128) {
    // ---- fused linear (z @ w_l1 + b_l1) + BN1 + upsample2x -> I ----
    int ch = blockIdx.x;
    float* red = smem;
    int hw = tid & 63, b0 = tid >> 6;
    int j = ch * 64 + hw;
    float acc0 = bl1[j], acc1 = acc0;
    const float* zp0 = z + b0 * 100;
    const float* zp1 = z + (b0 + 4) * 100;
    for (int l = 0; l < 100; ++l) {
      float wv = wl1[l * 8192 + j];
      acc0 += zp0[l] * wv;
      acc1 += zp1[l] * wv;
    }
    float v0 = acc0, v1 = acc1;
    red[tid] = v0 + v1; __syncthreads();
    for (int s = 128; s > 0; s >>= 1) { if (tid < s) red[tid] += red[tid + s]; __syncthreads(); }
    float mean = red[0] * (1.0f / 512.0f);
    __syncthreads();
    float d0 = v0 - mean, d1 = v1 - mean;
    red[tid] = d0 * d0 + d1 * d1; __syncthreads();
    for (int s = 128; s > 0; s >>= 1) { if (tid < s) red[tid] += red[tid + s]; __syncthreads(); }
    float var = red[0] * (1.0f / 512.0f);
    float coef = g1[ch] / sqrtf(var + 1e-5f);
    float beta = be1[ch];
    float q0 = (v0 - mean) * coef + beta;
    float q1 = (v1 - mean) * coef + beta;
#pragma unroll
    for (int k = 0; k < 2; ++k) {
      int n = k ? (tid + 256) : tid; float q = k ? q1 : q0;
      int b = n >> 6, hh = n & 63, h = hh >> 3, ww = hh & 7;
      float* o = I + (size_t)(b * 128 + ch) * 256 + (2 * h) * 16 + 2 * ww;
      o[0] = q; o[1] = q; o[16] = q; o[17] = q;
    }
  } else {
    // ---- weight transform: w_c1 fp32 -> wT[tap][oc][c] f16, u32 writes ----
    int wid = blockIdx.x - 128;
    float (*t)[2304] = (float(*)[2304])smem;
    int op = wid / 100, cg = wid % 100;
    int oc0 = op * 2, c0 = cg * 256;
    const float* src = wc1 + (size_t)oc0 * 230400 + (size_t)c0 * 9;
#pragma unroll
    for (int i = 0; i < 9; ++i) {
      t[0][tid + i * 256] = src[tid + i * 256];
      t[1][tid + i * 256] = src[230400 + tid + i * 256];
    }
    __syncthreads();
    int oh = tid >> 7;           // oc sub-index (0/1)
    int cp = tid & 127;          // c pair: c = 2cp, 2cp+1
#pragma unroll
    for (int tap = 0; tap < 9; ++tap) {
      union { unsigned int u; _Float16 h[2]; } pk;
      pk.h[0] = (_Float16)t[oh][(2 * cp) * 9 + tap];
      pk.h[1] = (_Float16)t[oh][(2 * cp + 1) * 9 + tap];
      *(unsigned int*)((char*)wT +
          ((size_t)(tap * 128 + oc0 + oh) * WROW + c0 + 2 * cp) * 2) = pk.u;
    }
  }
}

// LIF with bit-packed transposed spike output + fused halo zeroing.
// spkTb[pos][col/8] bit (col&7), col = t*1024 + plane.
__global__ __launch_bounds__(256) void k_lif(
    const float* __restrict__ I, unsigned char* __restrict__ spkTb) {
  int g = blockIdx.x * 256 + threadIdx.x;
  if (g < 217600) {
    int hr = g / 3200;           // halo row index 0..67
    int i  = g - hr * 3200;      // u64 index within row
    int row;
    if (hr < 18)      row = hr;                    // top band a=0
    else if (hr < 36) row = 306 + (hr - 18);       // bottom band a=17
    else { int kk = hr - 36; row = ((kk >> 1) + 1) * 18 + ((kk & 1) ? 17 : 0); }
    *(unsigned long long*)(spkTb + (size_t)row * SROW + (size_t)i * 8) = 0ULL;
  }
  int px = g >> 10, plane = g & 1023;
  int lane = threadIdx.x & 63;
  float in = I[plane * 256 + px];
  int pos = ((px >> 4) + 1) * 18 + (px & 15) + 1;
  unsigned long long* wsrow =
      (unsigned long long*)(spkTb + (size_t)pos * SROW + ((plane - lane) >> 3));
  float mem = 0.0f;
  for (int t = 0; t < 200; ++t) {
    float reset = (mem > 1.0f) ? 1.0f : 0.0f;
    mem = 0.95f * mem + in - reset;
    unsigned long long m = __ballot(mem > 1.0f);
    if (lane == 0) wsrow[t * 16] = m;   // t*128 bytes
  }
}

// bit->f16 expand: byte b -> 8 halfs {0,1.0h}, via multiply-spread + v_perm.
__device__ inline void expandp(unsigned int b, AFrag& f) {
  unsigned int lo = ((b & 0xFu) * 0x00204081u) & 0x01010101u;
  unsigned int hi = ((b >> 4) * 0x00204081u) & 0x01010101u;
  lo *= 0x3Cu; hi *= 0x3Cu;
  f.u[0] = __builtin_amdgcn_perm(0u, lo, 0x01040004u);
  f.u[1] = __builtin_amdgcn_perm(0u, lo, 0x03040204u);
  f.u[2] = __builtin_amdgcn_perm(0u, hi, 0x01040004u);
  f.u[3] = __builtin_amdgcn_perm(0u, hi, 0x03040204u);
}

__device__ __forceinline__ void gll16(const void* g, void* l) {
  __builtin_amdgcn_global_load_lds(
      (const __attribute__((address_space(1))) unsigned int*)g,
      (__attribute__((address_space(3))) unsigned int*)l, 16, 0, 0);
}

// conv1 implicit GEMM (R14 structure, FROZEN -- measured 133us, 36% dense
// peak = 2-phase plain-HIP ceiling). grid 768 = 48 K-slices x (2 ocHalf x
// 8 b), XCD-grouped by slice; 256 thr / 4 waves. Block tile M64 x N256;
// wave = M64 x N64 (mt=4, nt=4). K-slice: whole 128-ch chunks
// q in [sl*25/6,(sl+1)*25/6) (4 or 5); NBS = 9 taps x qc. 2-phase loop,
// A dbuf in LDS (2x16KB), B per-bigstep. LDS A chunk [oc 64][ch 128] f16,
// 4-bit 16B-slot XOR swizzle (slot ^= oc&15) on source AND ds_read address.
__global__ __launch_bounds__(256, 3) void k_conv1_mfma(
    const unsigned char* __restrict__ spkTb, const _Float16* __restrict__ wT,
    _Float16* __restrict__ y1p) {
  // bijective XCD swizzle: 768 = 8 x 96; XCD x gets v in [96x, 96x+96)
  int v = (blockIdx.x & 7) * 96 + (blockIdx.x >> 3);
  int sl = v >> 4;                       // 0..47
  int r = v & 15;
  int half = r >> 3, b = r & 7;          // oc-half, single batch
  int tid = threadIdx.x;
  int wave = tid >> 6, lane = tid & 63;
  int quad = lane >> 4, l16 = lane & 15;
  int qs = quad * 8;
  int h0 = wave * 4;

  int q0 = (sl * 25) / 6;
  int qc = ((sl + 1) * 25) / 6 - q0;     // 4 or 5 chunks of 128 ch
  int NBS = 9 * qc;

  __shared__ _Float16 As[2][8192];   // 2 x 16 KB, [oc 64][ch 128] swizzled

  int ocl = tid >> 4;
  int sc0 = (tid & 15) ^ ocl;
  const char* srcA0 = (const char*)wT + (size_t)q0 * 256
                    + (size_t)(half * 64 + ocl) * (WROW * 2) + sc0 * 16;

  const unsigned char* rowp[4];
#pragma unroll
  for (int nt = 0; nt < 4; ++nt)
    rowp[nt] = spkTb + b * 3200 + q0 * 16
             + (size_t)((h0 + nt) * 18 + l16) * SROW;

  int dsb[4];
#pragma unroll
  for (int s = 0; s < 4; ++s)
    dsb[s] = l16 * 256 + ((s * 64 + quad * 16) ^ (l16 << 4));

  f32x4 acc[4][4] = {};                 // [mt][nt]

  // prologue: stage A(step 0: tap 0, qi 0) -> buffer 0
#pragma unroll
  for (int i = 0; i < 4; ++i)
    gll16(srcA0 + (size_t)i * (16 * WROW * 2), (char*)As + i * 4096 + wave * 1024);
  __syncthreads();

  int tap = 0, qi = 0;
  for (int k = 0; k < NBS; ++k) {
    int dh = tap / 3, dw = tap - dh * 3;
    uint4v bx[4];
    int boff = (dh * 18 + dw) * SROW + qi * 16;
#pragma unroll
    for (int nt = 0; nt < 4; ++nt)
      bx[nt] = *(const uint4v*)(rowp[nt] + boff);
    int qin = qi + 1, tapn = tap;
    if (qin == qc) { qin = 0; tapn = tap + 1; }
    if (k + 1 < NBS) {
      size_t aoff = (size_t)tapn * ((size_t)128 * WROW * 2) + (size_t)qin * 256;
      char* dst = (char*)As + ((k + 1) & 1) * 16384 + wave * 1024;
#pragma unroll
      for (int i = 0; i < 4; ++i)
        gll16(srcA0 + (size_t)i * (16 * WROW * 2) + aoff, dst + i * 4096);
    }
    const char* cA = (const char*)As + (k & 1) * 16384;
#pragma unroll
    for (int s = 0; s < 4; ++s) {
      AFrag a[4];
#pragma unroll
      for (int mt = 0; mt < 4; ++mt)
        a[mt].u4 = *(const uint4v*)(cA + dsb[s] + mt * 4096);
#pragma unroll
      for (int nt = 0; nt < 4; ++nt) {
        AFrag bf; expandp((bx[nt][s] >> qs) & 0xFFu, bf);
#pragma unroll
        for (int mt = 0; mt < 4; ++mt)
          acc[mt][nt] = __builtin_amdgcn_mfma_f32_16x16x32_f16(
              a[mt].h, bf.h, acc[mt][nt], 0, 0, 0);
      }
    }
    __syncthreads();
    tap = tapn; qi = qin;
  }

  // epilogue: f16 partials
  _Float16* ob = y1p + (size_t)(sl * 8 + b) * 32768 + half * 16384;
#pragma unroll
  for (int mt = 0; mt < 4; ++mt)
#pragma unroll
    for (int nt = 0; nt < 4; ++nt) {
      int px = (h0 + nt) * 16 + l16;
#pragma unroll
      for (int rr = 0; rr < 4; ++rr) {
        int oc = mt * 16 + quad * 4 + rr;
        ob[(size_t)oc * 256 + px] = (_Float16)acc[mt][nt][rr];
      }
    }
}

// BN2 (eps 0.8, stats over 2048) + 48-way y1p reduce + conv1 bias +
// leaky(0.2) + upsample2x + halo zero. Thread = 2 px x 4 batches (u32 loads).
__global__ __launch_bounds__(256) void k_bn2_up(
    const _Float16* __restrict__ y1p, const float* __restrict__ bc1,
    const float* __restrict__ g2, const float* __restrict__ be2,
    float* __restrict__ x2p) {
  int ch = blockIdx.x, tid = threadIdx.x;
  __shared__ float red[256];

  // halo zero: planes (b, ch), 132-elem ring each
  for (int e = tid; e < 1056; e += 256) {
    int b = e / 132, i = e - b * 132;
    int rr, cc;
    if (i < 34)       { rr = 0;       cc = i; }
    else if (i < 68)  { rr = 33;      cc = i - 34; }
    else if (i < 100) { rr = i - 67;  cc = 0; }
    else              { rr = i - 99;  cc = 33; }
    x2p[(size_t)(b * 128 + ch) * 1156 + rr * 34 + cc] = 0.0f;
  }

  int pp = tid & 127;          // px pair: px = 2pp, 2pp+1
  int bh = tid >> 7;           // batches bh*4 .. bh*4+3
  float bias = bc1[ch];
  float a[4][2] = {};
  const char* base = (const char*)y1p + ((size_t)ch * 256 + pp * 2) * 2
                   + (size_t)bh * 4 * 65536;
  for (int tl = 0; tl < 48; ++tl) {
    const char* q = base + (size_t)tl * 524288;
#pragma unroll
    for (int k = 0; k < 4; ++k) {
      union { unsigned int u; _Float16 h[2]; } cv;
      cv.u = *(const unsigned int*)(q + (size_t)k * 65536);
      a[k][0] += (float)cv.h[0];
      a[k][1] += (float)cv.h[1];
    }
  }
  float vv[4][2]; float s = 0.0f;
#pragma unroll
  for (int k = 0; k < 4; ++k)
#pragma unroll
    for (int e = 0; e < 2; ++e) { vv[k][e] = a[k][e] + bias; s += vv[k][e]; }

  red[tid] = s; __syncthreads();
  for (int st = 128; st > 0; st >>= 1) { if (tid < st) red[tid] += red[tid + st]; __syncthreads(); }
  float mean = red[0] * (1.0f / 2048.0f);
  __syncthreads();
  s = 0.0f;
#pragma unroll
  for (int k = 0; k < 4; ++k)
#pragma unroll
    for (int e = 0; e < 2; ++e) { float d = vv[k][e] - mean; s += d * d; }
  red[tid] = s; __syncthreads();
  for (int st = 128; st > 0; st >>= 1) { if (tid < st) red[tid] += red[tid + st]; __syncthreads(); }
  float var = red[0] * (1.0f / 2048.0f);
  float coef = g2[ch] / sqrtf(var + 0.8f);
  float beta = be2[ch];
#pragma unroll
  for (int k = 0; k < 4; ++k)
#pragma unroll
    for (int e = 0; e < 2; ++e) {
      int b = bh * 4 + k, px = pp * 2 + e, h = px >> 4, w = px & 15;
      float q = (vv[k][e] - mean) * coef + beta;
      q = (q >= 0.0f) ? q : 0.2f * q;
      float* o = x2p + (size_t)(b * 128 + ch) * 1156 + (2 * h + 1) * 34 + (2 * w + 1);
      o[0] = q; o[1] = q; o[34] = q; o[35] = q;
    }
}

// conv2: flat grid 512, b = id&7 (XCD-by-batch); octile = (id>>3)>>2,
// pq = (id>>3)&3. Thread = 1 px x 4 oc.
__global__ __launch_bounds__(256) void k_conv2(
    const float* __restrict__ x2p, const float* __restrict__ wc2,
    const float* __restrict__ bc2, float* __restrict__ y2) {
  int b = blockIdx.x & 7;
  int rem = blockIdx.x >> 3;
  int octile = rem >> 2, pq = rem & 3;
  int tid = threadIdx.x;
  int p = pq * 256 + tid, h = p >> 5, w = p & 31;
  float a0 = 0.0f, a1 = 0.0f, a2 = 0.0f, a3 = 0.0f;
  const float* base = x2p + (size_t)(b * 128) * 1156 + h * 34 + w;
  const float* wb = wc2 + (size_t)(octile * 4) * 128 * 9;
  for (int ch = 0; ch < 128; ++ch) {
    const float* pp = base + (size_t)ch * 1156;
    float s0 = pp[0],  s1 = pp[1],  s2 = pp[2];
    float s3 = pp[34], s4 = pp[35], s5 = pp[36];
    float s6 = pp[68], s7 = pp[69], s8 = pp[70];
    const float* w0 = wb + (size_t)ch * 9;
    const float* w1 = wb + (size_t)(128 + ch) * 9;
    const float* w2 = wb + (size_t)(256 + ch) * 9;
    const float* w3 = wb + (size_t)(384 + ch) * 9;
    a0 += s0*w0[0]+s1*w0[1]+s2*w0[2]+s3*w0[3]+s4*w0[4]+s5*w0[5]+s6*w0[6]+s7*w0[7]+s8*w0[8];
    a1 += s0*w1[0]+s1*w1[1]+s2*w1[2]+s3*w1[3]+s4*w1[4]+s5*w1[5]+s6*w1[6]+s7*w1[7]+s8*w1[8];
    a2 += s0*w2[0]+s1*w2[1]+s2*w2[2]+s3*w2[3]+s4*w2[4]+s5*w2[5]+s6*w2[6]+s7*w2[7]+s8*w2[8];
    a3 += s0*w3[0]+s1*w3[1]+s2*w3[2]+s3*w3[3]+s4*w3[4]+s5*w3[5]+s6*w3[6]+s7*w3[7]+s8*w3[8];
  }
  int oc0 = octile * 4;
  y2[(size_t)(b * 64 + oc0 + 0) * 1024 + p] = a0 + bc2[oc0 + 0];
  y2[(size_t)(b * 64 + oc0 + 1) * 1024 + p] = a1 + bc2[oc0 + 1];
  y2[(size_t)(b * 64 + oc0 + 2) * 1024 + p] = a2 + bc2[oc0 + 2];
  y2[(size_t)(b * 64 + oc0 + 3) * 1024 + p] = a3 + bc2[oc0 + 3];
}

// BN3 (eps 0.8, stats over 8192) + leaky -> padded y2n (+ own halo zero)
__global__ __launch_bounds__(256) void k_bn3(
    const float* __restrict__ y2, const float* __restrict__ g3,
    const float* __restrict__ be3, float* __restrict__ y2n) {
  int ch = blockIdx.x, tid = threadIdx.x;
  __shared__ float red[256];

  for (int e = tid; e < 1056; e += 256) {
    int b = e / 132, i = e - b * 132;
    int rr, cc;
    if (i < 34)       { rr = 0;       cc = i; }
    else if (i < 68)  { rr = 33;      cc = i - 34; }
    else if (i < 100) { rr = i - 67;  cc = 0; }
    else              { rr = i - 99;  cc = 33; }
    y2n[(size_t)(b * 64 + ch) * 1156 + rr * 34 + cc] = 0.0f;
  }

  float v[32]; float s = 0.0f;
#pragma unroll
  for (int k = 0; k < 32; ++k) {
    int n = tid + k * 256;  // n = b*1024 + px
    v[k] = y2[(size_t)((n >> 10) * 64 + ch) * 1024 + (n & 1023)];
    s += v[k];
  }
  red[tid] = s; __syncthreads();
  for (int st = 128; st > 0; st >>= 1) { if (tid < st) red[tid] += red[tid + st]; __syncthreads(); }
  float mean = red[0] * (1.0f / 8192.0f);
  __syncthreads();
  s = 0.0f;
#pragma unroll
  for (int k = 0; k < 32; ++k) { float d = v[k] - mean; s += d * d; }
  red[tid] = s; __syncthreads();
  for (int st = 128; st > 0; st >>= 1) { if (tid < st) red[tid] += red[tid + st]; __syncthreads(); }
  float var = red[0] * (1.0f / 8192.0f);
  float coef = g3[ch] / sqrtf(var + 0.8f);
  float beta = be3[ch];
#pragma unroll
  for (int k = 0; k < 32; ++k) {
    int n = tid + k * 256;
    int b = n >> 10, px = n & 1023, h = px >> 5, w = px & 31;
    float q = (v[k] - mean) * coef + beta;
    q = (q >= 0.0f) ? q : 0.2f * q;
    y2n[(size_t)(b * 64 + ch) * 1156 + (h + 1) * 34 + (w + 1)] = q;
  }
}

// conv3 (3 oc) + bias + tanh -> d_out (8,3,32,32).
// flat grid 128: b = id&7 (XCD-by-batch), pg = id>>3.
// 256 thr = 64 px x 4 ch-groups; LDS reduce.
__global__ __launch_bounds__(256) void k_conv3(
    const float* __restrict__ y2n, const float* __restrict__ wc3,
    const float* __restrict__ bc3, float* __restrict__ out) {
  int b = blockIdx.x & 7, pg = blockIdx.x >> 3;
  int tid = threadIdx.x;
  int pxl = tid & 63, cg = tid >> 6;
  int p = pg * 64 + pxl, h = p >> 5, w = p & 31;
  float a0 = 0.0f, a1 = 0.0f, a2 = 0.0f;
  const float* base = y2n + (size_t)(b * 64 + cg * 16) * 1156 + h * 34 + w;
  for (int c = 0; c < 16; ++c) {
    int ch = cg * 16 + c;
    const float* pp = base + (size_t)c * 1156;
    float s0 = pp[0],  s1 = pp[1],  s2 = pp[2];
    float s3 = pp[34], s4 = pp[35], s5 = pp[36];
    float s6 = pp[68], s7 = pp[69], s8 = pp[70];
    const float* w0 = wc3 + (size_t)ch * 9;
    const float* w1 = wc3 + (size_t)(64 + ch) * 9;
    const float* w2 = wc3 + (size_t)(128 + ch) * 9;
    a0 += s0*w0[0]+s1*w0[1]+s2*w0[2]+s3*w0[3]+s4*w0[4]+s5*w0[5]+s6*w0[6]+s7*w0[7]+s8*w0[8];
    a1 += s0*w1[0]+s1*w1[1]+s2*w1[2]+s3*w1[3]+s4*w1[4]+s5*w1[5]+s6*w1[6]+s7*w1[7]+s8*w1[8];
    a2 += s0*w2[0]+s1*w2[1]+s2*w2[2]+s3*w2[3]+s4*w2[4]+s5*w2[5]+s6*w2[6]+s7*w2[7]+s8*w2[8];
  }
  __shared__ float red[3][256];
  red[0][tid] = a0; red[1][tid] = a1; red[2][tid] = a2;
  __syncthreads();
  if (tid < 192) {
    int oc = tid >> 6, px = tid & 63;
    float sres = red[oc][px] + red[oc][px + 64] + red[oc][px + 128] + red[oc][px + 192];
    out[(size_t)(b * 3 + oc) * 1024 + pg * 64 + px] = tanhf(sres + bc3[oc]);
  }
}

extern "C" void kernel_launch(void* const* d_in, const int* in_sizes, int n_in,
                              void* d_out, int out_size, void* d_ws, size_t ws_size,
                              hipStream_t stream) {
  const float* z    = (const float*)d_in[0];
  const float* w_l1 = (const float*)d_in[1];
  const float* b_l1 = (const float*)d_in[2];
  const float* g1   = (const float*)d_in[3];
  const float* be1  = (const float*)d_in[4];
  const float* w_c1 = (const float*)d_in[5];
  const float* b_c1 = (const float*)d_in[6];
  const float* g2   = (const float*)d_in[7];
  const float* be2  = (const float*)d_in[8];
  const float* w_c2 = (const float*)d_in[9];
  const float* b_c2 = (const float*)d_in[10];
  const float* g3   = (const float*)d_in[11];
  const float* be3  = (const float*)d_in[12];
  const float* w_c3 = (const float*)d_in[13];
  const float* b_c3 = (const float*)d_in[14];
  float* out = (float*)d_out;

  char* ws = (char*)d_ws;
  // phase A
  _Float16* wT = (_Float16*)ws;                             // 59,056,128 B
  unsigned char* spkTb = (unsigned char*)(ws + 59056128);   //  8,315,136 B
  float* I   = (float*)(ws + 67633408);                     //  1,048,576 B
  _Float16* y1p = (_Float16*)(ws + 69730560);               // 25,165,824 B
  // phase B (aliases wT region; written only after conv1 completes)
  float* x2p = (float*)ws;                                  //  4,734,976 B
  float* y2n = (float*)(ws + 4734976);                      //  2,367,488 B
  float* y2  = (float*)(ws + 7102464);                      //  2,097,152 B

  k_pre    <<<6528, 256, 0, stream>>>(w_c1, wT, z, w_l1, b_l1, g1, be1, I);
  k_lif    <<<1024, 256, 0, stream>>>(I, spkTb);
  k_conv1_mfma<<<768, 256, 0, stream>>>(spkTb, wT, y1p);

  k_bn2_up <<<128, 256, 0, stream>>>(y1p, b_c1, g2, be2, x2p);
  k_conv2  <<<512, 256, 0, stream>>>(x2p, w_c2, b_c2, y2);
  k_bn3    <<<64, 256, 0, stream>>>(y2, g3, be3, y2n);
  k_conv3  <<<128, 256, 0, stream>>>(y2n, w_c3, b_c3, out);
}